// Round 3
// baseline (994.788 us; speedup 1.0000x reference)
//
#include <hip/hip_runtime.h>
#include <cstdint>

#define S_LEN   1024
#define D_DIM   512
#define H_HEADS 8
#define B_BATCH 4
#define NEGV    -1000000000.0f

typedef __bf16 bf16;
typedef __bf16 bf16x8 __attribute__((ext_vector_type(8)));
typedef __bf16 bf16x4 __attribute__((ext_vector_type(4)));
typedef float  f32x4  __attribute__((ext_vector_type(4)));

// async global->LDS, 16B per lane (wave-uniform LDS base + lane*16 semantics)
#define GLL16(gp, lp) __builtin_amdgcn_global_load_lds( \
    (const __attribute__((address_space(1))) void*)(gp), \
    (__attribute__((address_space(3))) void*)(lp), 16, 0, 0)

// ---------------------------------------------------------------------------
// Generic bf16 GEMM, C = A @ B^T (+bias), both operands row-major K-contiguous.
// 128x128 tile, BK=32, 4 waves (2x2), wave tile 64x64 = 4x4 frags of 16x16x32.
// MODE 0: bf16 natural row-major out (+bias)
// MODE 1: bf16 [h,s,d] permuted out (+bias)    (per-batch proj Q,K; h=n>>9)
// MODE 2: bf16 [h,d,s] transposed out (+bias)  (per-batch proj V -> Vt)
// MODE 3: f32 natural out (+optional bias)     (PV out, final out)
// MODE 4: bf16 scores out: v*scale, mask==0 -> NEG
// ---------------------------------------------------------------------------
template<int MODE>
__global__ __launch_bounds__(256) void gemm_bt(
    const bf16* __restrict__ A, const bf16* __restrict__ B,
    void* __restrict__ Cout, const float* __restrict__ bias,
    const int* __restrict__ mask,
    int N, int K, long zsA, long zsB, long zsC, float scale, int Hh)
{
  const int z = blockIdx.z;
  A += (long)z * zsA;
  B += (long)z * zsB;

  const int bm0 = blockIdx.x * 128;
  const int bn0 = blockIdx.y * 128;

  __shared__ __attribute__((aligned(16))) bf16 As[128 * 32];
  __shared__ __attribute__((aligned(16))) bf16 Bs[128 * 32];

  const int tid  = threadIdx.x;
  const int wid  = tid >> 6;
  const int lane = tid & 63;
  const int wm = (wid >> 1) * 64;
  const int wn = (wid & 1) * 64;

  // staging: 256 threads x 16B = 4KB/issue; 2 issues per 128x32 bf16 tile
  const int srow = tid >> 2;
  const int scol = (tid & 3) * 8;
  const bf16* gA0 = A + (long)(bm0 + srow) * K + scol;
  const bf16* gA1 = A + (long)(bm0 + 64 + srow) * K + scol;
  const bf16* gB0 = B + (long)(bn0 + srow) * K + scol;
  const bf16* gB1 = B + (long)(bn0 + 64 + srow) * K + scol;
  bf16* lA0 = As + tid * 8;
  bf16* lA1 = As + 2048 + tid * 8;
  bf16* lB0 = Bs + tid * 8;
  bf16* lB1 = Bs + 2048 + tid * 8;

  // fragment addressing: lane l reads row (l&15), k = (l>>4)*8 .. +7
  const int lrow = lane & 15;
  const int lk   = (lane >> 4) * 8;
  const bf16* fA = As + (wm + lrow) * 32 + lk;
  const bf16* fB = Bs + (wn + lrow) * 32 + lk;

  f32x4 acc[4][4] = {};

  for (int k0 = 0; k0 < K; k0 += 32) {
    GLL16(gA0 + k0, lA0);
    GLL16(gA1 + k0, lA1);
    GLL16(gB0 + k0, lB0);
    GLL16(gB1 + k0, lB1);
    __syncthreads();   // compiler drains vmcnt before barrier (m97 pattern)
    bf16x8 af[4], bfr[4];
#pragma unroll
    for (int i = 0; i < 4; ++i) af[i]  = *(const bf16x8*)(fA + i * 16 * 32);
#pragma unroll
    for (int i = 0; i < 4; ++i) bfr[i] = *(const bf16x8*)(fB + i * 16 * 32);
#pragma unroll
    for (int mi = 0; mi < 4; ++mi)
#pragma unroll
      for (int ni = 0; ni < 4; ++ni)
        acc[mi][ni] = __builtin_amdgcn_mfma_f32_16x16x32_bf16(
            af[mi], bfr[ni], acc[mi][ni], 0, 0, 0);
    __syncthreads();
  }

  // C/D layout (m89 verified): col = lane&15, row = (lane>>4)*4 + reg
  const int r0 = (lane >> 4) << 2;
  const int cn = lane & 15;

#pragma unroll
  for (int mi = 0; mi < 4; ++mi) {
#pragma unroll
    for (int ni = 0; ni < 4; ++ni) {
      const int n = bn0 + wn + ni * 16 + cn;
      float bv = 0.f;
      if constexpr (MODE != 4) { if (bias) bv = bias[n]; }
      int mk = 1;
      if constexpr (MODE == 4) mk = mask[(z / Hh) * S_LEN + n];
#pragma unroll
      for (int r = 0; r < 4; ++r) {
        const int m = bm0 + wm + mi * 16 + r0 + r;
        float v = acc[mi][ni][r];
        if constexpr (MODE == 0) {
          ((bf16*)Cout)[(long)z * zsC + (long)m * N + n] = (bf16)(v + bv);
        } else if constexpr (MODE == 1) {
          long o = ((long)(n >> 9) * S_LEN + m) * D_DIM + (n & (D_DIM - 1));
          ((bf16*)Cout)[o] = (bf16)(v + bv);
        } else if constexpr (MODE == 2) {
          long o = ((long)(n >> 9) * D_DIM + (n & (D_DIM - 1))) * S_LEN + m;
          ((bf16*)Cout)[o] = (bf16)(v + bv);
        } else if constexpr (MODE == 3) {
          ((float*)Cout)[(long)z * zsC + (long)m * N + n] = v + bv;
        } else {
          float sv = (mk == 0) ? NEGV : v * scale;
          ((bf16*)Cout)[(long)z * zsC + (long)m * N + n] = (bf16)sv;
        }
      }
    }
  }
}

// ---------------------------------------------------------------------------
// row softmax in place over 1024 bf16 entries per row (fp32 math)
// ---------------------------------------------------------------------------
__global__ __launch_bounds__(256) void softmax_rows(bf16* __restrict__ buf)
{
  const long row = blockIdx.x;
  bf16* p = buf + row * S_LEN;
  const int tid = threadIdx.x;
  const int wid = tid >> 6, lane = tid & 63;
  bf16x4 raw = *(const bf16x4*)(p + tid * 4);
  float v[4];
#pragma unroll
  for (int j = 0; j < 4; ++j) v[j] = (float)raw[j];
  float mx = fmaxf(fmaxf(v[0], v[1]), fmaxf(v[2], v[3]));
  for (int m = 32; m; m >>= 1) mx = fmaxf(mx, __shfl_xor(mx, m, 64));
  __shared__ float red[4];
  if (lane == 0) red[wid] = mx;
  __syncthreads();
  mx = fmaxf(fmaxf(red[0], red[1]), fmaxf(red[2], red[3]));
  float e[4]; float s = 0.f;
#pragma unroll
  for (int j = 0; j < 4; ++j) { e[j] = __expf(v[j] - mx); s += e[j]; }
  for (int m = 32; m; m >>= 1) s += __shfl_xor(s, m, 64);
  __syncthreads();
  if (lane == 0) red[wid] = s;
  __syncthreads();
  s = red[0] + red[1] + red[2] + red[3];
  const float inv = 1.f / s;
  bf16x4 o;
#pragma unroll
  for (int j = 0; j < 4; ++j) o[j] = (bf16)(e[j] * inv);
  *(bf16x4*)(p + tid * 4) = o;
}

// ---------------------------------------------------------------------------
// per s (one batch): dis_h = ||x_h - xp||^2, w = softmax(1/(dis+1e-9)),
// mixed = 0.8*sum_h w_h x_h + 0.2*xp
// writes row s of MIXb: [0:512]=hi(mixed), [512:1024]=lo(mixed), [1024:1536]=hi
// X layout [h,s,d] fp32; XP [s,d] fp32.
// ---------------------------------------------------------------------------
__global__ __launch_bounds__(256) void combine_kernel(
    const float* __restrict__ X, const float* __restrict__ XP,
    bf16* __restrict__ MIXb)
{
  const int s = blockIdx.x;
  const int tid = threadIdx.x;
  const int wid = tid >> 6, lane = tid & 63;
  const float2 xp = *(const float2*)(XP + (long)s * D_DIM + tid * 2);
  float xv0[H_HEADS], xv1[H_HEADS], part[H_HEADS];
#pragma unroll
  for (int h = 0; h < H_HEADS; ++h) {
    const float* xrow = X + ((long)h * S_LEN + s) * D_DIM;
    float2 t = *(const float2*)(xrow + tid * 2);
    xv0[h] = t.x; xv1[h] = t.y;
    float d0 = t.x - xp.x, d1 = t.y - xp.y;
    part[h] = d0 * d0 + d1 * d1;
  }
  __shared__ float red[4][H_HEADS];
#pragma unroll
  for (int h = 0; h < H_HEADS; ++h) {
    float v = part[h];
    for (int mm = 32; mm; mm >>= 1) v += __shfl_xor(v, mm, 64);
    if (lane == 0) red[wid][h] = v;
  }
  __syncthreads();
  float w[H_HEADS]; float mx = -1e30f;
#pragma unroll
  for (int h = 0; h < H_HEADS; ++h) {
    float dis = red[0][h] + red[1][h] + red[2][h] + red[3][h];
    w[h] = 1.f / (dis + 1e-9f);
    mx = fmaxf(mx, w[h]);
  }
  float ssum = 0.f;
#pragma unroll
  for (int h = 0; h < H_HEADS; ++h) { w[h] = __expf(w[h] - mx); ssum += w[h]; }
  const float inv = 1.f / ssum;
  float m0 = 0.f, m1 = 0.f;
#pragma unroll
  for (int h = 0; h < H_HEADS; ++h) { m0 += w[h] * xv0[h]; m1 += w[h] * xv1[h]; }
  m0 = 0.8f * m0 * inv + 0.2f * xp.x;
  m1 = 0.8f * m1 * inv + 0.2f * xp.y;
  const bf16 h0 = (bf16)m0, h1 = (bf16)m1;
  const bf16 l0 = (bf16)(m0 - (float)h0), l1 = (bf16)(m1 - (float)h1);
  bf16* orow = MIXb + (long)s * 1536;
  orow[tid * 2]        = h0; orow[tid * 2 + 1]        = h1;
  orow[512 + tid * 2]  = l0; orow[512 + tid * 2 + 1]  = l1;
  orow[1024 + tid * 2] = h0; orow[1024 + tid * 2 + 1] = h1;
}

// fp32 -> bf16 convert, 3 tensors selected by blockIdx.z, 8 elems/thread
__global__ __launch_bounds__(256) void cvt3_kernel(
    const float* __restrict__ s0, const float* __restrict__ s1, const float* __restrict__ s2,
    bf16* __restrict__ d0, bf16* __restrict__ d1, bf16* __restrict__ d2)
{
  const float* s = blockIdx.z == 0 ? s0 : (blockIdx.z == 1 ? s1 : s2);
  bf16* d       = blockIdx.z == 0 ? d0 : (blockIdx.z == 1 ? d1 : d2);
  const long i = ((long)blockIdx.x * 256 + threadIdx.x) * 8;
  float4 a = *(const float4*)(s + i);
  float4 b = *(const float4*)(s + i + 4);
  bf16x8 o;
  o[0]=(bf16)a.x; o[1]=(bf16)a.y; o[2]=(bf16)a.z; o[3]=(bf16)a.w;
  o[4]=(bf16)b.x; o[5]=(bf16)b.y; o[6]=(bf16)b.z; o[7]=(bf16)b.w;
  *(bf16x8*)(d + i) = o;
}

// transpose (R x C fp32) -> (C x R bf16)
// TRIPLE=0: plain transpose-convert, row stride R
// TRIPLE=1: row stride 3R; writes hi at +0, hi at +R, lo-residual at +2R
template<int TRIPLE>
__global__ __launch_bounds__(256) void transpose_cvt3(
    const float* __restrict__ s0, const float* __restrict__ s1, const float* __restrict__ s2,
    bf16* __restrict__ d0, bf16* __restrict__ d1, bf16* __restrict__ d2,
    int R, int C)
{
  const float* src = blockIdx.z == 0 ? s0 : (blockIdx.z == 1 ? s1 : s2);
  bf16* dst       = blockIdx.z == 0 ? d0 : (blockIdx.z == 1 ? d1 : d2);
  __shared__ float t[32][33];
  const int tc = threadIdx.x & 31;
  const int tr = threadIdx.x >> 5;
  const int c0 = blockIdx.x * 32, r0 = blockIdx.y * 32;
#pragma unroll
  for (int i = 0; i < 4; ++i)
    t[tr + 8 * i][tc] = src[(long)(r0 + tr + 8 * i) * C + c0 + tc];
  __syncthreads();
  const int RD = TRIPLE ? 3 * R : R;
#pragma unroll
  for (int i = 0; i < 4; ++i) {
    float v = t[tc][tr + 8 * i];
    long o = (long)(c0 + tr + 8 * i) * RD + r0 + tc;
    const bf16 hi = (bf16)v;
    dst[o] = hi;
    if (TRIPLE) {
      dst[o + R] = hi;
      dst[o + 2 * R] = (bf16)(v - (float)hi);
    }
  }
}

// ---------------------------------------------------------------------------
extern "C" void kernel_launch(void* const* d_in, const int* in_sizes, int n_in,
                              void* d_out, int out_size, void* d_ws, size_t ws_size,
                              hipStream_t stream) {
  const float* query  = (const float*)d_in[0];
  const float* key    = (const float*)d_in[1];
  const float* value  = (const float*)d_in[2];
  const int*   mask   = (const int*)d_in[3];
  const int*   mask_p = (const int*)d_in[4];
  const float* Wq  = (const float*)d_in[5];  const float* bq  = (const float*)d_in[6];
  const float* Wk  = (const float*)d_in[7];  const float* bk  = (const float*)d_in[8];
  const float* Wv  = (const float*)d_in[9];  const float* bv  = (const float*)d_in[10];
  const float* Wpq = (const float*)d_in[11]; const float* bpq = (const float*)d_in[12];
  const float* Wpk = (const float*)d_in[13]; const float* bpk = (const float*)d_in[14];
  const float* Wpv = (const float*)d_in[15]; const float* bpv = (const float*)d_in[16];
  const float* Wo  = (const float*)d_in[17]; const float* bo  = (const float*)d_in[18];

  char* ws = (char*)d_ws;
  size_t off = 0;
  auto alloc = [&](size_t bytes) -> void* {
    void* p = ws + off;
    off += (bytes + 255) & ~(size_t)255;
    return p;
  };
  const long BS  = (long)B_BATCH * S_LEN;         // 4096
  const long ZSD = (long)S_LEN * D_DIM;           // 524288
  const long ZSS = (long)S_LEN * S_LEN;           // 1048576

  // persistent
  bf16* XQ16 = (bf16*)alloc(BS * D_DIM * 2);
  bf16* XK16 = (bf16*)alloc(BS * D_DIM * 2);
  bf16* XV16 = (bf16*)alloc(BS * D_DIM * 2);
  bf16* WQT  = (bf16*)alloc((long)H_HEADS * D_DIM * D_DIM * 2);
  bf16* WKT  = (bf16*)alloc((long)H_HEADS * D_DIM * D_DIM * 2);
  bf16* WVT  = (bf16*)alloc((long)H_HEADS * D_DIM * D_DIM * 2);
  bf16* WPQT = (bf16*)alloc((long)D_DIM * D_DIM * 2);
  bf16* WPKT = (bf16*)alloc((long)D_DIM * D_DIM * 2);
  bf16* WPVT = (bf16*)alloc((long)D_DIM * D_DIM * 2);
  bf16* WOT3 = (bf16*)alloc((long)D_DIM * 3 * D_DIM * 2);
  bf16* MIX  = (bf16*)alloc(BS * 1536 * 2);
  // per-batch (reused each iteration; stream ordering serializes)
  bf16* Qb   = (bf16*)alloc((long)H_HEADS * ZSD * 2);
  bf16* Kb   = (bf16*)alloc((long)H_HEADS * ZSD * 2);
  bf16* VTb  = (bf16*)alloc((long)H_HEADS * ZSD * 2);
  bf16* QPb  = (bf16*)alloc(ZSD * 2);
  bf16* KPb  = (bf16*)alloc(ZSD * 2);
  bf16* VPTb = (bf16*)alloc(ZSD * 2);
  bf16* SCb  = (bf16*)alloc((long)H_HEADS * ZSS * 2);
  bf16* SCPb = (bf16*)alloc(ZSS * 2);
  float* Xb  = (float*)alloc((long)H_HEADS * ZSD * 4);
  float* XPb = (float*)alloc(ZSD * 4);
  (void)in_sizes; (void)n_in; (void)out_size;

  // ws overflow guard: skip all work -> clean absmax failure (diagnostic),
  // never an OOB write.
  if (off > ws_size) return;

  const dim3 blk(256);
  const float scale = 0.044194173824159216f;  // 1/sqrt(512)

  // 1. convert inputs to bf16 (full, once)
  cvt3_kernel<<<dim3(1024, 1, 3), blk, 0, stream>>>(query, key, value, XQ16, XK16, XV16);
  // 2. transpose-convert weights (once)
  transpose_cvt3<0><<<dim3(128, 16, 3), blk, 0, stream>>>(Wq, Wk, Wv, WQT, WKT, WVT, 512, 4096);
  transpose_cvt3<0><<<dim3(16, 16, 3), blk, 0, stream>>>(Wpq, Wpk, Wpv, WPQT, WPKT, WPVT, 512, 512);
  transpose_cvt3<1><<<dim3(16, 16, 1), blk, 0, stream>>>(Wo, Wo, Wo, WOT3, WOT3, WOT3, 512, 512);

  for (int b = 0; b < B_BATCH; ++b) {
    const bf16* xq = XQ16 + (long)b * ZSD;
    const bf16* xk = XK16 + (long)b * ZSD;
    const bf16* xv = XV16 + (long)b * ZSD;
    // 3. per-batch projections (M=1024)
    gemm_bt<1><<<dim3(8, 32, 1), blk, 0, stream>>>(xq, WQT, Qb, bq, nullptr, 4096, 512, 0, 0, 0, 1.f, H_HEADS);
    gemm_bt<1><<<dim3(8, 32, 1), blk, 0, stream>>>(xk, WKT, Kb, bk, nullptr, 4096, 512, 0, 0, 0, 1.f, H_HEADS);
    gemm_bt<2><<<dim3(8, 32, 1), blk, 0, stream>>>(xv, WVT, VTb, bv, nullptr, 4096, 512, 0, 0, 0, 1.f, H_HEADS);
    gemm_bt<0><<<dim3(8, 4, 1), blk, 0, stream>>>(xq, WPQT, QPb, bpq, nullptr, 512, 512, 0, 0, 0, 1.f, 1);
    gemm_bt<0><<<dim3(8, 4, 1), blk, 0, stream>>>(xk, WPKT, KPb, bpk, nullptr, 512, 512, 0, 0, 0, 1.f, 1);
    gemm_bt<2><<<dim3(8, 4, 1), blk, 0, stream>>>(xv, WPVT, VPTb, bpv, nullptr, 512, 512, 0, 0, 0, 1.f, 1);

    // 4. scores = QK^T * scale, masked  (z = head)
    gemm_bt<4><<<dim3(8, 8, H_HEADS), blk, 0, stream>>>(Qb, Kb, SCb, nullptr, mask + (long)b * S_LEN,
                                                        1024, 512, ZSD, ZSD, ZSS, scale, H_HEADS);
    gemm_bt<4><<<dim3(8, 8, 1), blk, 0, stream>>>(QPb, KPb, SCPb, nullptr, mask_p + (long)b * S_LEN,
                                                  1024, 512, ZSD, ZSD, ZSS, scale, 1);

    // 5. softmax rows in place
    softmax_rows<<<dim3(H_HEADS * S_LEN), blk, 0, stream>>>(SCb);
    softmax_rows<<<dim3(S_LEN), blk, 0, stream>>>(SCPb);

    // 6. x = P @ V  (fp32 out, layout [h,s,d])
    gemm_bt<3><<<dim3(8, 4, H_HEADS), blk, 0, stream>>>(SCb, VTb, Xb, nullptr, nullptr, 512, 1024, ZSS, ZSD, ZSD, 1.f, 1);
    gemm_bt<3><<<dim3(8, 4, 1), blk, 0, stream>>>(SCPb, VPTb, XPb, nullptr, nullptr, 512, 1024, ZSS, ZSD, ZSD, 1.f, 1);

    // 7. dis / head softmax / mix -> [hi|lo|hi] rows of MIX for this batch
    combine_kernel<<<dim3(S_LEN), blk, 0, stream>>>(Xb, XPb, MIX + (long)b * S_LEN * 1536);
  }

  // 8. out = [m_hi|m_lo|m_hi] @ [Wo_hi|Wo_hi|Wo_lo]^T + bo  (fp32 out)
  //    = mixed @ Wo + bo minus the negligible m_lo@Wo_lo term
  gemm_bt<3><<<dim3(32, 4, 1), blk, 0, stream>>>(MIX, WOT3, d_out, bo, nullptr, 512, 1536, 0, 0, 0, 1.f, 1);
}

// Round 4
// 524.126 us; speedup vs baseline: 1.8980x; 1.8980x over previous
//
#include <hip/hip_runtime.h>
#include <cstdint>

#define S_LEN   1024
#define D_DIM   512
#define H_HEADS 8
#define B_BATCH 4
#define NEGV    -1000000000.0f

typedef __bf16 bf16;
typedef __bf16 bf16x8 __attribute__((ext_vector_type(8)));
typedef __bf16 bf16x4 __attribute__((ext_vector_type(4)));
typedef float  f32x4  __attribute__((ext_vector_type(4)));

// async global->LDS, 16B per lane (wave-uniform LDS base + lane*16 semantics)
#define GLL16(gp, lp) __builtin_amdgcn_global_load_lds( \
    (const __attribute__((address_space(1))) void*)(gp), \
    (__attribute__((address_space(3))) void*)(lp), 16, 0, 0)

// ---------------------------------------------------------------------------
// Generic bf16 GEMM, C = A @ B^T (+bias), both operands row-major K-contiguous.
// 128x128 tile, BK=32, 4 waves (2x2), wave tile 64x64 = 4x4 frags of 16x16x32.
// z (blockIdx.z) strides A/B/C by zsA/zsB/zsC elements (tensor- or batch-select).
// MODE 0: bf16 natural row-major out (+bias; bias2 used when z==1)
// MODE 1: bf16 [b,h,s,d] out (+bias)            (proj Q,K; b=m>>10, h=n>>9)
// MODE 2: bf16 [b,h,d,s] transposed out (+bias) (proj V -> Vt)
// MODE 3: f32 natural out (+optional bias)      (PV out, final out)
// MODE 4: bf16 scores out: v*scale, mask==0 -> NEG  (mask row = z/Hh)
// ---------------------------------------------------------------------------
template<int MODE>
__global__ __launch_bounds__(256) void gemm_bt(
    const bf16* __restrict__ A, const bf16* __restrict__ B,
    void* __restrict__ Cout, const float* __restrict__ bias,
    const float* __restrict__ bias2, const int* __restrict__ mask,
    int N, int K, long zsA, long zsB, long zsC, float scale, int Hh)
{
  const int z = blockIdx.z;
  A += (long)z * zsA;
  B += (long)z * zsB;

  const int bm0 = blockIdx.x * 128;
  const int bn0 = blockIdx.y * 128;

  __shared__ __attribute__((aligned(16))) bf16 As[128 * 32];
  __shared__ __attribute__((aligned(16))) bf16 Bs[128 * 32];

  const int tid  = threadIdx.x;
  const int wid  = tid >> 6;
  const int lane = tid & 63;
  const int wm = (wid >> 1) * 64;
  const int wn = (wid & 1) * 64;

  // staging: 256 threads x 16B = 4KB/issue; 2 issues per 128x32 bf16 tile
  const int srow = tid >> 2;
  const int scol = (tid & 3) * 8;
  const bf16* gA0 = A + (long)(bm0 + srow) * K + scol;
  const bf16* gA1 = A + (long)(bm0 + 64 + srow) * K + scol;
  const bf16* gB0 = B + (long)(bn0 + srow) * K + scol;
  const bf16* gB1 = B + (long)(bn0 + 64 + srow) * K + scol;
  bf16* lA0 = As + tid * 8;
  bf16* lA1 = As + 2048 + tid * 8;
  bf16* lB0 = Bs + tid * 8;
  bf16* lB1 = Bs + 2048 + tid * 8;

  // fragment addressing: lane l reads row (l&15), k = (l>>4)*8 .. +7
  const int lrow = lane & 15;
  const int lk   = (lane >> 4) * 8;
  const bf16* fA = As + (wm + lrow) * 32 + lk;
  const bf16* fB = Bs + (wn + lrow) * 32 + lk;

  f32x4 acc[4][4] = {};

  for (int k0 = 0; k0 < K; k0 += 32) {
    GLL16(gA0 + k0, lA0);
    GLL16(gA1 + k0, lA1);
    GLL16(gB0 + k0, lB0);
    GLL16(gB1 + k0, lB1);
    __syncthreads();   // compiler drains vmcnt before barrier (m97 pattern)
    bf16x8 af[4], bfr[4];
#pragma unroll
    for (int i = 0; i < 4; ++i) af[i]  = *(const bf16x8*)(fA + i * 16 * 32);
#pragma unroll
    for (int i = 0; i < 4; ++i) bfr[i] = *(const bf16x8*)(fB + i * 16 * 32);
#pragma unroll
    for (int mi = 0; mi < 4; ++mi)
#pragma unroll
      for (int ni = 0; ni < 4; ++ni)
        acc[mi][ni] = __builtin_amdgcn_mfma_f32_16x16x32_bf16(
            af[mi], bfr[ni], acc[mi][ni], 0, 0, 0);
    __syncthreads();
  }

  // C/D layout (m89 verified): col = lane&15, row = (lane>>4)*4 + reg
  const int r0 = (lane >> 4) << 2;
  const int cn = lane & 15;

#pragma unroll
  for (int mi = 0; mi < 4; ++mi) {
#pragma unroll
    for (int ni = 0; ni < 4; ++ni) {
      const int n = bn0 + wn + ni * 16 + cn;
      float bv = 0.f;
      if constexpr (MODE != 4) {
        const float* bp = (z == 1 && bias2) ? bias2 : bias;
        if (bp) bv = bp[n];
      }
      int mk = 1;
      if constexpr (MODE == 4) mk = mask[(z / Hh) * S_LEN + n];
#pragma unroll
      for (int r = 0; r < 4; ++r) {
        const int m = bm0 + wm + mi * 16 + r0 + r;
        float v = acc[mi][ni][r];
        if constexpr (MODE == 0) {
          ((bf16*)Cout)[(long)z * zsC + (long)m * N + n] = (bf16)(v + bv);
        } else if constexpr (MODE == 1) {
          long o = (long)z * zsC +
                   (((long)(m >> 10) * Hh + (n >> 9)) * S_LEN + (m & (S_LEN - 1))) * D_DIM
                   + (n & (D_DIM - 1));
          ((bf16*)Cout)[o] = (bf16)(v + bv);
        } else if constexpr (MODE == 2) {
          long o = (long)z * zsC +
                   (((long)(m >> 10) * Hh + (n >> 9)) * D_DIM + (n & (D_DIM - 1))) * S_LEN
                   + (m & (S_LEN - 1));
          ((bf16*)Cout)[o] = (bf16)(v + bv);
        } else if constexpr (MODE == 3) {
          ((float*)Cout)[(long)z * zsC + (long)m * N + n] = v + bv;
        } else {
          float sv = (mk == 0) ? NEGV : v * scale;
          ((bf16*)Cout)[(long)z * zsC + (long)m * N + n] = (bf16)sv;
        }
      }
    }
  }
}

// ---------------------------------------------------------------------------
// row softmax in place over 1024 bf16 entries per row (fp32 math)
// ---------------------------------------------------------------------------
__global__ __launch_bounds__(256) void softmax_rows(bf16* __restrict__ buf)
{
  const long row = blockIdx.x;
  bf16* p = buf + row * S_LEN;
  const int tid = threadIdx.x;
  const int wid = tid >> 6, lane = tid & 63;
  bf16x4 raw = *(const bf16x4*)(p + tid * 4);
  float v[4];
#pragma unroll
  for (int j = 0; j < 4; ++j) v[j] = (float)raw[j];
  float mx = fmaxf(fmaxf(v[0], v[1]), fmaxf(v[2], v[3]));
  for (int m = 32; m; m >>= 1) mx = fmaxf(mx, __shfl_xor(mx, m, 64));
  __shared__ float red[4];
  if (lane == 0) red[wid] = mx;
  __syncthreads();
  mx = fmaxf(fmaxf(red[0], red[1]), fmaxf(red[2], red[3]));
  float e[4]; float s = 0.f;
#pragma unroll
  for (int j = 0; j < 4; ++j) { e[j] = __expf(v[j] - mx); s += e[j]; }
  for (int m = 32; m; m >>= 1) s += __shfl_xor(s, m, 64);
  __syncthreads();
  if (lane == 0) red[wid] = s;
  __syncthreads();
  s = red[0] + red[1] + red[2] + red[3];
  const float inv = 1.f / s;
  bf16x4 o;
#pragma unroll
  for (int j = 0; j < 4; ++j) o[j] = (bf16)(e[j] * inv);
  *(bf16x4*)(p + tid * 4) = o;
}

// ---------------------------------------------------------------------------
// per (b,s): dis_h = ||x_h - xp||^2, w = softmax(1/(dis+1e-9)),
// mixed = 0.8*sum_h w_h x_h + 0.2*xp
// X layout [(b*H+h), s, d] fp32; XP [(b), s, d] fp32.
// writes row (b*S+s) of MIX: [0:512]=hi, [512:1024]=lo, [1024:1536]=hi
// ---------------------------------------------------------------------------
__global__ __launch_bounds__(256) void combine_kernel(
    const float* __restrict__ X, const float* __restrict__ XP,
    bf16* __restrict__ MIX)
{
  const int m = blockIdx.x;            // b*S + s
  const int b = m >> 10;
  const int s = m & (S_LEN - 1);
  const int tid = threadIdx.x;
  const int wid = tid >> 6, lane = tid & 63;
  const float2 xp = *(const float2*)(XP + (long)m * D_DIM + tid * 2);
  float xv0[H_HEADS], xv1[H_HEADS], part[H_HEADS];
#pragma unroll
  for (int h = 0; h < H_HEADS; ++h) {
    const float* xrow = X + ((long)(b * H_HEADS + h) * S_LEN + s) * D_DIM;
    float2 t = *(const float2*)(xrow + tid * 2);
    xv0[h] = t.x; xv1[h] = t.y;
    float d0 = t.x - xp.x, d1 = t.y - xp.y;
    part[h] = d0 * d0 + d1 * d1;
  }
  __shared__ float red[4][H_HEADS];
#pragma unroll
  for (int h = 0; h < H_HEADS; ++h) {
    float v = part[h];
    for (int mm = 32; mm; mm >>= 1) v += __shfl_xor(v, mm, 64);
    if (lane == 0) red[wid][h] = v;
  }
  __syncthreads();
  float w[H_HEADS]; float mx = -1e30f;
#pragma unroll
  for (int h = 0; h < H_HEADS; ++h) {
    float dis = red[0][h] + red[1][h] + red[2][h] + red[3][h];
    w[h] = 1.f / (dis + 1e-9f);
    mx = fmaxf(mx, w[h]);
  }
  float ssum = 0.f;
#pragma unroll
  for (int h = 0; h < H_HEADS; ++h) { w[h] = __expf(w[h] - mx); ssum += w[h]; }
  const float inv = 1.f / ssum;
  float m0 = 0.f, m1 = 0.f;
#pragma unroll
  for (int h = 0; h < H_HEADS; ++h) { m0 += w[h] * xv0[h]; m1 += w[h] * xv1[h]; }
  m0 = 0.8f * m0 * inv + 0.2f * xp.x;
  m1 = 0.8f * m1 * inv + 0.2f * xp.y;
  const bf16 h0 = (bf16)m0, h1 = (bf16)m1;
  const bf16 l0 = (bf16)(m0 - (float)h0), l1 = (bf16)(m1 - (float)h1);
  bf16* orow = MIX + (long)m * 1536;
  orow[tid * 2]        = h0; orow[tid * 2 + 1]        = h1;
  orow[512 + tid * 2]  = l0; orow[512 + tid * 2 + 1]  = l1;
  orow[1024 + tid * 2] = h0; orow[1024 + tid * 2 + 1] = h1;
}

// fp32 -> bf16 convert, 3 tensors selected by blockIdx.z, 8 elems/thread
__global__ __launch_bounds__(256) void cvt3_kernel(
    const float* __restrict__ s0, const float* __restrict__ s1, const float* __restrict__ s2,
    bf16* __restrict__ d0, bf16* __restrict__ d1, bf16* __restrict__ d2)
{
  const float* s = blockIdx.z == 0 ? s0 : (blockIdx.z == 1 ? s1 : s2);
  bf16* d       = blockIdx.z == 0 ? d0 : (blockIdx.z == 1 ? d1 : d2);
  const long i = ((long)blockIdx.x * 256 + threadIdx.x) * 8;
  float4 a = *(const float4*)(s + i);
  float4 b = *(const float4*)(s + i + 4);
  bf16x8 o;
  o[0]=(bf16)a.x; o[1]=(bf16)a.y; o[2]=(bf16)a.z; o[3]=(bf16)a.w;
  o[4]=(bf16)b.x; o[5]=(bf16)b.y; o[6]=(bf16)b.z; o[7]=(bf16)b.w;
  *(bf16x8*)(d + i) = o;
}

// transpose (R x C fp32) -> (C x R bf16)
// TRIPLE=0: plain transpose-convert, row stride R
// TRIPLE=1: row stride 3R; writes hi at +0, hi at +R, lo-residual at +2R
template<int TRIPLE>
__global__ __launch_bounds__(256) void transpose_cvt3(
    const float* __restrict__ s0, const float* __restrict__ s1, const float* __restrict__ s2,
    bf16* __restrict__ d0, bf16* __restrict__ d1, bf16* __restrict__ d2,
    int R, int C)
{
  const float* src = blockIdx.z == 0 ? s0 : (blockIdx.z == 1 ? s1 : s2);
  bf16* dst       = blockIdx.z == 0 ? d0 : (blockIdx.z == 1 ? d1 : d2);
  __shared__ float t[32][33];
  const int tc = threadIdx.x & 31;
  const int tr = threadIdx.x >> 5;
  const int c0 = blockIdx.x * 32, r0 = blockIdx.y * 32;
#pragma unroll
  for (int i = 0; i < 4; ++i)
    t[tr + 8 * i][tc] = src[(long)(r0 + tr + 8 * i) * C + c0 + tc];
  __syncthreads();
  const int RD = TRIPLE ? 3 * R : R;
#pragma unroll
  for (int i = 0; i < 4; ++i) {
    float v = t[tc][tr + 8 * i];
    long o = (long)(c0 + tr + 8 * i) * RD + r0 + tc;
    const bf16 hi = (bf16)v;
    dst[o] = hi;
    if (TRIPLE) {
      dst[o + R] = hi;
      dst[o + 2 * R] = (bf16)(v - (float)hi);
    }
  }
}

// ---------------------------------------------------------------------------
extern "C" void kernel_launch(void* const* d_in, const int* in_sizes, int n_in,
                              void* d_out, int out_size, void* d_ws, size_t ws_size,
                              hipStream_t stream) {
  const float* query  = (const float*)d_in[0];
  const float* key    = (const float*)d_in[1];
  const float* value  = (const float*)d_in[2];
  const int*   mask   = (const int*)d_in[3];
  const int*   mask_p = (const int*)d_in[4];
  const float* Wq  = (const float*)d_in[5];  const float* bq  = (const float*)d_in[6];
  const float* Wk  = (const float*)d_in[7];  const float* bk  = (const float*)d_in[8];
  const float* Wv  = (const float*)d_in[9];  const float* bv  = (const float*)d_in[10];
  const float* Wpq = (const float*)d_in[11]; const float* bpq = (const float*)d_in[12];
  const float* Wpk = (const float*)d_in[13]; const float* bpk = (const float*)d_in[14];
  const float* Wpv = (const float*)d_in[15]; const float* bpv = (const float*)d_in[16];
  const float* Wo  = (const float*)d_in[17]; const float* bo  = (const float*)d_in[18];

  char* ws = (char*)d_ws;
  size_t off = 0;
  auto alloc = [&](size_t bytes) -> void* {
    void* p = ws + off;
    off += (bytes + 255) & ~(size_t)255;
    return p;
  };
  const long BS  = (long)B_BATCH * S_LEN;         // 4096
  const long ZSD = (long)S_LEN * D_DIM;           // 524288
  const long ZSS = (long)S_LEN * S_LEN;           // 1048576
  const long SD  = BS * D_DIM;                    // 2097152 (one 4096x512 tensor)

  // --- workspace plan (207 MB of 256 MiB), with explicit aliasing ---
  // weights
  bf16* WQT  = (bf16*)alloc(SD * 2);              // adjacent WQT,WKT -> z-stride SD
  bf16* WKT  = (bf16*)alloc(SD * 2);
  bf16* WVT  = (bf16*)alloc(SD * 2);
  bf16* WPQT = (bf16*)alloc((long)D_DIM * D_DIM * 2);  // adjacent WPQT,WPKT
  bf16* WPKT = (bf16*)alloc((long)D_DIM * D_DIM * 2);
  bf16* WPVT = (bf16*)alloc((long)D_DIM * D_DIM * 2);
  bf16* WOT3 = (bf16*)alloc((long)D_DIM * 3 * D_DIM * 2);
  // bf16 inputs; dead after projections -> MIX aliases (12 MiB == 12 MiB)
  bf16* XQ16 = (bf16*)alloc(SD * 2);              // adjacent XQ,XK (z-stride SD)
  bf16* XK16 = (bf16*)alloc(SD * 2);
  bf16* XV16 = (bf16*)alloc(SD * 2);
  bf16* MIX  = XQ16;                              // alias: 4096*1536*2 = 12 MiB
  // Q,K; dead after scores -> X (fp32, 64 MiB) aliases Q16+K16 (64 MiB)
  bf16* Q16  = (bf16*)alloc((long)H_HEADS * SD * 2);   // adjacent Q16,K16
  bf16* K16  = (bf16*)alloc((long)H_HEADS * SD * 2);
  float* X   = (float*)Q16;
  bf16* VT16 = (bf16*)alloc((long)H_HEADS * SD * 2);
  // p-branch; QP,KP dead after scores_p -> XP (fp32, 8 MiB) aliases (8 MiB)
  bf16* QP16 = (bf16*)alloc(SD * 2);              // adjacent QP,KP
  bf16* KP16 = (bf16*)alloc(SD * 2);
  float* XP  = (float*)QP16;
  bf16* VPT16= (bf16*)alloc(SD * 2);
  // scores (SC and SCP adjacent -> single softmax launch over both)
  bf16* SC   = (bf16*)alloc((long)B_BATCH * H_HEADS * ZSS * 2);
  bf16* SCP  = (bf16*)alloc((long)B_BATCH * ZSS * 2);
  (void)in_sizes; (void)n_in; (void)out_size; (void)SCP;

  // ws overflow guard: clean failure, never OOB
  if (off > ws_size) return;

  const dim3 blk(256);
  const float scale = 0.044194173824159216f;  // 1/sqrt(512)

  // 1. inputs -> bf16
  cvt3_kernel<<<dim3(1024, 1, 3), blk, 0, stream>>>(query, key, value, XQ16, XK16, XV16);
  // 2. weights -> transposed bf16
  transpose_cvt3<0><<<dim3(128, 16, 3), blk, 0, stream>>>(Wq, Wk, Wv, WQT, WKT, WVT, 512, 4096);
  transpose_cvt3<0><<<dim3(16, 16, 3), blk, 0, stream>>>(Wpq, Wpk, Wpv, WPQT, WPKT, WPVT, 512, 512);
  transpose_cvt3<1><<<dim3(16, 16, 1), blk, 0, stream>>>(Wo, Wo, Wo, WOT3, WOT3, WOT3, 512, 512);

  // 3. projections, full batch (M=4096)
  //    Q+K in one launch: z in {0,1} selects (XQ16|XK16) x (WQT|WKT) -> (Q16|K16)
  gemm_bt<1><<<dim3(32, 32, 2), blk, 0, stream>>>(XQ16, WQT, Q16, bq, bk, nullptr,
      4096, 512, SD, SD, (long)H_HEADS * SD, 1.f, H_HEADS);
  gemm_bt<2><<<dim3(32, 32, 1), blk, 0, stream>>>(XV16, WVT, VT16, bv, nullptr, nullptr,
      4096, 512, 0, 0, 0, 1.f, H_HEADS);
  //    p-branch Q+K in one launch
  gemm_bt<0><<<dim3(32, 4, 2), blk, 0, stream>>>(XQ16, WPQT, QP16, bpq, bpk, nullptr,
      512, 512, SD, (long)D_DIM * D_DIM, SD, 1.f, 1);
  gemm_bt<2><<<dim3(32, 4, 1), blk, 0, stream>>>(XV16, WPVT, VPT16, bpv, nullptr, nullptr,
      512, 512, 0, 0, 0, 1.f, 1);

  // 4. scores = QK^T * scale, masked (z = b*H+h for main, b for p)
  gemm_bt<4><<<dim3(8, 8, 32), blk, 0, stream>>>(Q16, K16, SC, nullptr, nullptr, mask,
      1024, 512, ZSD, ZSD, ZSS, scale, H_HEADS);
  gemm_bt<4><<<dim3(8, 8, 4), blk, 0, stream>>>(QP16, KP16, SCP, nullptr, nullptr, mask_p,
      1024, 512, ZSD, ZSD, ZSS, scale, 1);

  // 5. softmax over SC and SCP together (adjacent rows)
  softmax_rows<<<dim3(32768 + 4096), blk, 0, stream>>>(SC);

  // 6. x = P @ V  (fp32 out; X aliases Q16/K16 — dead after step 4)
  gemm_bt<3><<<dim3(8, 4, 32), blk, 0, stream>>>(SC, VT16, X, nullptr, nullptr, nullptr,
      512, 1024, ZSS, ZSD, ZSD, 1.f, 1);
  gemm_bt<3><<<dim3(8, 4, 4), blk, 0, stream>>>(SCP, VPT16, XP, nullptr, nullptr, nullptr,
      512, 1024, ZSS, ZSD, ZSD, 1.f, 1);

  // 7. dis / head softmax / mix -> [hi|lo|hi] rows (MIX aliases XQ/XK/XV)
  combine_kernel<<<dim3(4096), blk, 0, stream>>>(X, XP, MIX);

  // 8. out = [m_hi|m_lo|m_hi] @ [Wo_hi|Wo_hi|Wo_lo]^T + bo  (fp32 out)
  gemm_bt<3><<<dim3(32, 4, 1), blk, 0, stream>>>(MIX, WOT3, d_out, bo, nullptr, nullptr,
      512, 1536, 0, 0, 0, 1.f, 1);
}

// Round 5
// 477.666 us; speedup vs baseline: 2.0826x; 1.0973x over previous
//
#include <hip/hip_runtime.h>
#include <cstdint>

#define S_LEN   1024
#define D_DIM   512
#define H_HEADS 8
#define B_BATCH 4
#define NEGV    -1000000000.0f

typedef __bf16 bf16;
typedef __bf16 bf16x8 __attribute__((ext_vector_type(8)));
typedef __bf16 bf16x4 __attribute__((ext_vector_type(4)));
typedef float  f32x4  __attribute__((ext_vector_type(4)));

// async global->LDS, 16B per lane (wave-uniform LDS base + lane*16 semantics)
#define GLL16(gp, lp) __builtin_amdgcn_global_load_lds( \
    (const __attribute__((address_space(1))) void*)(gp), \
    (__attribute__((address_space(3))) void*)(lp), 16, 0, 0)

// counted vmcnt wait (T4) — literal N, memory clobber so LDS reads can't cross
#define VMW(N) asm volatile("s_waitcnt vmcnt(" #N ")" ::: "memory")
// barrier with compiler memory fences (raw s_barrier, no vmcnt drain)
#define BARM() do { asm volatile("" ::: "memory"); \
                    __builtin_amdgcn_s_barrier();  \
                    asm volatile("" ::: "memory"); } while (0)

// ---------------------------------------------------------------------------
// 256x256 8-wave pipelined GEMM, C = A @ B^T (+bias). BK=32, 4-deep LDS
// rotation, counted vmcnt (never 0 in main loop), frag-packed lane-linear LDS
// (bank-conflict-free ds_read_b128), setprio around MFMA clusters, bijective
// XCD-chunked block swizzle. Requires M%256==0, N%256==0, K%32==0, K>=128.
// MODE 1: bf16 [b,h,s,d] out (+bias/bias2 by z)   (proj Q,K)
// MODE 2: bf16 [b,h,d,s] transposed out (+bias)   (proj V -> Vt)
// MODE 3: f32 natural out                          (PV out)
// MODE 4: bf16 scores out: v*scale, mask==0 -> NEG
// ---------------------------------------------------------------------------
template<int MODE>
__global__ __launch_bounds__(512, 2) void gemm256_bt(
    const bf16* __restrict__ A, const bf16* __restrict__ B,
    void* __restrict__ Cout, const float* __restrict__ bias,
    const float* __restrict__ bias2, const int* __restrict__ mask,
    int N, int K, long zsA, long zsB, long zsC, float scale, int Hh)
{
  // T1: bijective XCD-chunked swizzle over the flattened grid (m204)
  const int gx = gridDim.x, gy = gridDim.y;
  const int nwg = gx * gy * gridDim.z;
  int bid = blockIdx.x + gx * (blockIdx.y + gy * blockIdx.z);
  {
    const int q = nwg >> 3, r = nwg & 7;
    const int xcd = bid & 7, idx = bid >> 3;
    bid = (xcd < r ? xcd * (q + 1) : r * (q + 1) + (xcd - r) * q) + idx;
  }
  const int bx = bid % gx;
  const int by = (bid / gx) % gy;
  const int z  = bid / (gx * gy);

  A += (long)z * zsA;
  B += (long)z * zsB;
  const int bm0 = bx * 256;
  const int bn0 = by * 256;

  // 4 rotating buffers; per buffer: A frags [0:8192), B frags [8192:16384)
  // (each 128-row half = 8 frags x 512 elems; frag = 1KiB lane-linear block)
  __shared__ __attribute__((aligned(16))) bf16 LDS[4 * 16384];  // 128 KiB

  const int tid  = threadIdx.x;
  const int wid  = tid >> 6;
  const int lane = tid & 63;
  const int wr = wid >> 2;        // 0..1: wave M-half
  const int wc = wid & 3;         // 0..3: wave N-quarter

  // staging source (pre-permuted per-lane so LDS lands lane-linear):
  // lane l stages (row = l&15, k-chunk = l>>4) of frag `wid` of each half
  const long arow = (long)(bm0 + wid * 16 + (lane & 15)) * K + ((lane >> 4) * 8);
  const long brow = (long)(bn0 + wid * 16 + (lane & 15)) * K + ((lane >> 4) * 8);
  const long rstep = 128L * (long)K;   // +128 rows (second half)

  auto stageA = [&](int tt) {          // 2 per-wave gloads (A half0, half1)
    bf16* d = LDS + (tt & 3) * 16384 + wid * 512;
    const bf16* g = A + arow + (long)tt * 32;
    GLL16(g, d);
    GLL16(g + rstep, d + 4096);
  };
  auto stageB = [&](int tt) {          // 2 per-wave gloads (B half0, half1)
    bf16* d = LDS + (tt & 3) * 16384 + 8192 + wid * 512;
    const bf16* g = B + brow + (long)tt * 32;
    GLL16(g, d);
    GLL16(g + rstep, d + 4096);
  };

  f32x4 acc[8][4] = {};
  const int NT = K >> 5;               // K-tiles of 32

  // prologue: stage tiles 0,1,2 (12 per-wave loads); retire tile 0 (oldest 4)
  stageA(0); stageB(0);
  stageA(1); stageB(1);
  stageA(2); stageB(2);
  VMW(8);
  BARM();

  for (int t = 0; t < NT; ++t) {
    const bf16* bufp = LDS + (t & 3) * 16384;
    const bf16* ap = bufp + wr * 4096 + lane * 8;          // A frags, own half
    const bf16* bp = bufp + 8192 + wc * 2048 + lane * 8;   // B frags, own 64

    // ---- phase 0: stage A(t+3) | read A frags 0-3 + B frags | 16 MFMA ----
    if (t + 3 < NT) stageA(t + 3);
    bf16x8 a0[4], bb[4];
#pragma unroll
    for (int i = 0; i < 4; ++i) a0[i] = *(const bf16x8*)(ap + i * 512);
#pragma unroll
    for (int i = 0; i < 4; ++i) bb[i] = *(const bf16x8*)(bp + i * 512);
    BARM();
    __builtin_amdgcn_s_setprio(1);
#pragma unroll
    for (int mi = 0; mi < 4; ++mi)
#pragma unroll
      for (int ni = 0; ni < 4; ++ni)
        acc[mi][ni] = __builtin_amdgcn_mfma_f32_16x16x32_bf16(
            a0[mi], bb[ni], acc[mi][ni], 0, 0, 0);
    __builtin_amdgcn_s_setprio(0);
    BARM();

    // ---- phase 1: stage B(t+3) | read A frags 4-7 | 16 MFMA | vmcnt gate ---
    if (t + 3 < NT) stageB(t + 3);
    bf16x8 a1[4];
#pragma unroll
    for (int i = 0; i < 4; ++i) a1[i] = *(const bf16x8*)(ap + (4 + i) * 512);
    BARM();
    __builtin_amdgcn_s_setprio(1);
#pragma unroll
    for (int mi = 0; mi < 4; ++mi)
#pragma unroll
      for (int ni = 0; ni < 4; ++ni)
        acc[4 + mi][ni] = __builtin_amdgcn_mfma_f32_16x16x32_bf16(
            a1[mi], bb[ni], acc[4 + mi][ni], 0, 0, 0);
    __builtin_amdgcn_s_setprio(0);
    // gate: tile t+1 must be fully resident after the barrier.
    // outstanding worst-case here = tiles t+1,t+2,t+3 (12 loads) -> vmcnt(8)
    if (t <= NT - 4)      VMW(8);
    else if (t == NT - 3) VMW(4);
    else if (t == NT - 2) VMW(0);
    BARM();
  }

  // epilogue: C/D layout col = lane&15, row = (lane>>4)*4 + reg (m89)
  const int r0 = (lane >> 4) << 2;
  const int cn = lane & 15;

#pragma unroll
  for (int mi = 0; mi < 8; ++mi) {
#pragma unroll
    for (int ni = 0; ni < 4; ++ni) {
      const int n = bn0 + wc * 64 + ni * 16 + cn;
      float bv = 0.f;
      if constexpr (MODE != 4) {
        const float* bp2 = (z == 1 && bias2) ? bias2 : bias;
        if (bp2) bv = bp2[n];
      }
      int mk = 1;
      if constexpr (MODE == 4) mk = mask[(z / Hh) * S_LEN + n];
#pragma unroll
      for (int r = 0; r < 4; ++r) {
        const int m = bm0 + wr * 128 + mi * 16 + r0 + r;
        float v = acc[mi][ni][r];
        if constexpr (MODE == 1) {
          long o = (long)z * zsC +
                   (((long)(m >> 10) * Hh + (n >> 9)) * S_LEN + (m & (S_LEN - 1))) * D_DIM
                   + (n & (D_DIM - 1));
          ((bf16*)Cout)[o] = (bf16)(v + bv);
        } else if constexpr (MODE == 2) {
          long o = (long)z * zsC +
                   (((long)(m >> 10) * Hh + (n >> 9)) * D_DIM + (n & (D_DIM - 1))) * S_LEN
                   + (m & (S_LEN - 1));
          ((bf16*)Cout)[o] = (bf16)(v + bv);
        } else if constexpr (MODE == 3) {
          ((float*)Cout)[(long)z * zsC + (long)m * N + n] = v + bv;
        } else {
          float sv = (mk == 0) ? NEGV : v * scale;
          ((bf16*)Cout)[(long)z * zsC + (long)m * N + n] = (bf16)sv;
        }
      }
    }
  }
}

// ---------------------------------------------------------------------------
// 128x128 m97-structure GEMM (proven) — used for small shapes.
// MODE 0: bf16 natural row-major out (+bias; bias2 used when z==1)
// MODE 2: bf16 [b,h,d,s] transposed out (+bias)
// MODE 3: f32 natural out (+optional bias)
// MODE 4: bf16 scores out: v*scale, mask==0 -> NEG
// ---------------------------------------------------------------------------
template<int MODE>
__global__ __launch_bounds__(256) void gemm_bt(
    const bf16* __restrict__ A, const bf16* __restrict__ B,
    void* __restrict__ Cout, const float* __restrict__ bias,
    const float* __restrict__ bias2, const int* __restrict__ mask,
    int N, int K, long zsA, long zsB, long zsC, float scale, int Hh)
{
  const int z = blockIdx.z;
  A += (long)z * zsA;
  B += (long)z * zsB;

  const int bm0 = blockIdx.x * 128;
  const int bn0 = blockIdx.y * 128;

  __shared__ __attribute__((aligned(16))) bf16 As[128 * 32];
  __shared__ __attribute__((aligned(16))) bf16 Bs[128 * 32];

  const int tid  = threadIdx.x;
  const int wid  = tid >> 6;
  const int lane = tid & 63;
  const int wm = (wid >> 1) * 64;
  const int wn = (wid & 1) * 64;

  const int srow = tid >> 2;
  const int scol = (tid & 3) * 8;
  const bf16* gA0 = A + (long)(bm0 + srow) * K + scol;
  const bf16* gA1 = A + (long)(bm0 + 64 + srow) * K + scol;
  const bf16* gB0 = B + (long)(bn0 + srow) * K + scol;
  const bf16* gB1 = B + (long)(bn0 + 64 + srow) * K + scol;
  bf16* lA0 = As + tid * 8;
  bf16* lA1 = As + 2048 + tid * 8;
  bf16* lB0 = Bs + tid * 8;
  bf16* lB1 = Bs + 2048 + tid * 8;

  const int lrow = lane & 15;
  const int lk   = (lane >> 4) * 8;
  const bf16* fA = As + (wm + lrow) * 32 + lk;
  const bf16* fB = Bs + (wn + lrow) * 32 + lk;

  f32x4 acc[4][4] = {};

  for (int k0 = 0; k0 < K; k0 += 32) {
    GLL16(gA0 + k0, lA0);
    GLL16(gA1 + k0, lA1);
    GLL16(gB0 + k0, lB0);
    GLL16(gB1 + k0, lB1);
    __syncthreads();
    bf16x8 af[4], bfr[4];
#pragma unroll
    for (int i = 0; i < 4; ++i) af[i]  = *(const bf16x8*)(fA + i * 16 * 32);
#pragma unroll
    for (int i = 0; i < 4; ++i) bfr[i] = *(const bf16x8*)(fB + i * 16 * 32);
#pragma unroll
    for (int mi = 0; mi < 4; ++mi)
#pragma unroll
      for (int ni = 0; ni < 4; ++ni)
        acc[mi][ni] = __builtin_amdgcn_mfma_f32_16x16x32_bf16(
            af[mi], bfr[ni], acc[mi][ni], 0, 0, 0);
    __syncthreads();
  }

  const int r0 = (lane >> 4) << 2;
  const int cn = lane & 15;

#pragma unroll
  for (int mi = 0; mi < 4; ++mi) {
#pragma unroll
    for (int ni = 0; ni < 4; ++ni) {
      const int n = bn0 + wn + ni * 16 + cn;
      float bv = 0.f;
      if constexpr (MODE != 4) {
        const float* bp = (z == 1 && bias2) ? bias2 : bias;
        if (bp) bv = bp[n];
      }
      int mk = 1;
      if constexpr (MODE == 4) mk = mask[(z / Hh) * S_LEN + n];
#pragma unroll
      for (int r = 0; r < 4; ++r) {
        const int m = bm0 + wm + mi * 16 + r0 + r;
        float v = acc[mi][ni][r];
        if constexpr (MODE == 0) {
          ((bf16*)Cout)[(long)z * zsC + (long)m * N + n] = (bf16)(v + bv);
        } else if constexpr (MODE == 2) {
          long o = (long)z * zsC +
                   (((long)(m >> 10) * Hh + (n >> 9)) * D_DIM + (n & (D_DIM - 1))) * S_LEN
                   + (m & (S_LEN - 1));
          ((bf16*)Cout)[o] = (bf16)(v + bv);
        } else if constexpr (MODE == 3) {
          ((float*)Cout)[(long)z * zsC + (long)m * N + n] = v + bv;
        } else if constexpr (MODE == 4) {
          float sv = (mk == 0) ? NEGV : v * scale;
          ((bf16*)Cout)[(long)z * zsC + (long)m * N + n] = (bf16)sv;
        }
      }
    }
  }
}

// ---------------------------------------------------------------------------
// row softmax in place over 1024 bf16 entries per row (fp32 math)
// ---------------------------------------------------------------------------
__global__ __launch_bounds__(256) void softmax_rows(bf16* __restrict__ buf)
{
  const long row = blockIdx.x;
  bf16* p = buf + row * S_LEN;
  const int tid = threadIdx.x;
  const int wid = tid >> 6, lane = tid & 63;
  bf16x4 raw = *(const bf16x4*)(p + tid * 4);
  float v[4];
#pragma unroll
  for (int j = 0; j < 4; ++j) v[j] = (float)raw[j];
  float mx = fmaxf(fmaxf(v[0], v[1]), fmaxf(v[2], v[3]));
  for (int m = 32; m; m >>= 1) mx = fmaxf(mx, __shfl_xor(mx, m, 64));
  __shared__ float red[4];
  if (lane == 0) red[wid] = mx;
  __syncthreads();
  mx = fmaxf(fmaxf(red[0], red[1]), fmaxf(red[2], red[3]));
  float e[4]; float s = 0.f;
#pragma unroll
  for (int j = 0; j < 4; ++j) { e[j] = __expf(v[j] - mx); s += e[j]; }
  for (int m = 32; m; m >>= 1) s += __shfl_xor(s, m, 64);
  __syncthreads();
  if (lane == 0) red[wid] = s;
  __syncthreads();
  s = red[0] + red[1] + red[2] + red[3];
  const float inv = 1.f / s;
  bf16x4 o;
#pragma unroll
  for (int j = 0; j < 4; ++j) o[j] = (bf16)(e[j] * inv);
  *(bf16x4*)(p + tid * 4) = o;
}

// ---------------------------------------------------------------------------
// per (b,s): dis_h = ||x_h - xp||^2, w = softmax(1/(dis+1e-9)),
// mixed = 0.8*sum_h w_h x_h + 0.2*xp
// writes row (b*S+s) of MIX: [0:512]=hi, [512:1024]=lo, [1024:1536]=hi
// ---------------------------------------------------------------------------
__global__ __launch_bounds__(256) void combine_kernel(
    const float* __restrict__ X, const float* __restrict__ XP,
    bf16* __restrict__ MIX)
{
  const int m = blockIdx.x;            // b*S + s
  const int b = m >> 10;
  const int s = m & (S_LEN - 1);
  const int tid = threadIdx.x;
  const int wid = tid >> 6, lane = tid & 63;
  const float2 xp = *(const float2*)(XP + (long)m * D_DIM + tid * 2);
  float xv0[H_HEADS], xv1[H_HEADS], part[H_HEADS];
#pragma unroll
  for (int h = 0; h < H_HEADS; ++h) {
    const float* xrow = X + ((long)(b * H_HEADS + h) * S_LEN + s) * D_DIM;
    float2 t = *(const float2*)(xrow + tid * 2);
    xv0[h] = t.x; xv1[h] = t.y;
    float d0 = t.x - xp.x, d1 = t.y - xp.y;
    part[h] = d0 * d0 + d1 * d1;
  }
  __shared__ float red[4][H_HEADS];
#pragma unroll
  for (int h = 0; h < H_HEADS; ++h) {
    float v = part[h];
    for (int mm = 32; mm; mm >>= 1) v += __shfl_xor(v, mm, 64);
    if (lane == 0) red[wid][h] = v;
  }
  __syncthreads();
  float w[H_HEADS]; float mx = -1e30f;
#pragma unroll
  for (int h = 0; h < H_HEADS; ++h) {
    float dis = red[0][h] + red[1][h] + red[2][h] + red[3][h];
    w[h] = 1.f / (dis + 1e-9f);
    mx = fmaxf(mx, w[h]);
  }
  float ssum = 0.f;
#pragma unroll
  for (int h = 0; h < H_HEADS; ++h) { w[h] = __expf(w[h] - mx); ssum += w[h]; }
  const float inv = 1.f / ssum;
  float m0 = 0.f, m1 = 0.f;
#pragma unroll
  for (int h = 0; h < H_HEADS; ++h) { m0 += w[h] * xv0[h]; m1 += w[h] * xv1[h]; }
  m0 = 0.8f * m0 * inv + 0.2f * xp.x;
  m1 = 0.8f * m1 * inv + 0.2f * xp.y;
  const bf16 h0 = (bf16)m0, h1 = (bf16)m1;
  const bf16 l0 = (bf16)(m0 - (float)h0), l1 = (bf16)(m1 - (float)h1);
  bf16* orow = MIX + (long)m * 1536;
  orow[tid * 2]        = h0; orow[tid * 2 + 1]        = h1;
  orow[512 + tid * 2]  = l0; orow[512 + tid * 2 + 1]  = l1;
  orow[1024 + tid * 2] = h0; orow[1024 + tid * 2 + 1] = h1;
}

// fp32 -> bf16 convert, 3 tensors selected by blockIdx.z, 8 elems/thread
__global__ __launch_bounds__(256) void cvt3_kernel(
    const float* __restrict__ s0, const float* __restrict__ s1, const float* __restrict__ s2,
    bf16* __restrict__ d0, bf16* __restrict__ d1, bf16* __restrict__ d2)
{
  const float* s = blockIdx.z == 0 ? s0 : (blockIdx.z == 1 ? s1 : s2);
  bf16* d       = blockIdx.z == 0 ? d0 : (blockIdx.z == 1 ? d1 : d2);
  const long i = ((long)blockIdx.x * 256 + threadIdx.x) * 8;
  float4 a = *(const float4*)(s + i);
  float4 b = *(const float4*)(s + i + 4);
  bf16x8 o;
  o[0]=(bf16)a.x; o[1]=(bf16)a.y; o[2]=(bf16)a.z; o[3]=(bf16)a.w;
  o[4]=(bf16)b.x; o[5]=(bf16)b.y; o[6]=(bf16)b.z; o[7]=(bf16)b.w;
  *(bf16x8*)(d + i) = o;
}

// transpose (R x C fp32) -> (C x R bf16)
// TRIPLE=0: plain transpose-convert, row stride R
// TRIPLE=1: row stride 3R; writes hi at +0, hi at +R, lo-residual at +2R
template<int TRIPLE>
__global__ __launch_bounds__(256) void transpose_cvt3(
    const float* __restrict__ s0, const float* __restrict__ s1, const float* __restrict__ s2,
    bf16* __restrict__ d0, bf16* __restrict__ d1, bf16* __restrict__ d2,
    int R, int C)
{
  const float* src = blockIdx.z == 0 ? s0 : (blockIdx.z == 1 ? s1 : s2);
  bf16* dst       = blockIdx.z == 0 ? d0 : (blockIdx.z == 1 ? d1 : d2);
  __shared__ float t[32][33];
  const int tc = threadIdx.x & 31;
  const int tr = threadIdx.x >> 5;
  const int c0 = blockIdx.x * 32, r0 = blockIdx.y * 32;
#pragma unroll
  for (int i = 0; i < 4; ++i)
    t[tr + 8 * i][tc] = src[(long)(r0 + tr + 8 * i) * C + c0 + tc];
  __syncthreads();
  const int RD = TRIPLE ? 3 * R : R;
#pragma unroll
  for (int i = 0; i < 4; ++i) {
    float v = t[tc][tr + 8 * i];
    long o = (long)(c0 + tr + 8 * i) * RD + r0 + tc;
    const bf16 hi = (bf16)v;
    dst[o] = hi;
    if (TRIPLE) {
      dst[o + R] = hi;
      dst[o + 2 * R] = (bf16)(v - (float)hi);
    }
  }
}

// ---------------------------------------------------------------------------
extern "C" void kernel_launch(void* const* d_in, const int* in_sizes, int n_in,
                              void* d_out, int out_size, void* d_ws, size_t ws_size,
                              hipStream_t stream) {
  const float* query  = (const float*)d_in[0];
  const float* key    = (const float*)d_in[1];
  const float* value  = (const float*)d_in[2];
  const int*   mask   = (const int*)d_in[3];
  const int*   mask_p = (const int*)d_in[4];
  const float* Wq  = (const float*)d_in[5];  const float* bq  = (const float*)d_in[6];
  const float* Wk  = (const float*)d_in[7];  const float* bk  = (const float*)d_in[8];
  const float* Wv  = (const float*)d_in[9];  const float* bv  = (const float*)d_in[10];
  const float* Wpq = (const float*)d_in[11]; const float* bpq = (const float*)d_in[12];
  const float* Wpk = (const float*)d_in[13]; const float* bpk = (const float*)d_in[14];
  const float* Wpv = (const float*)d_in[15]; const float* bpv = (const float*)d_in[16];
  const float* Wo  = (const float*)d_in[17]; const float* bo  = (const float*)d_in[18];

  char* ws = (char*)d_ws;
  size_t off = 0;
  auto alloc = [&](size_t bytes) -> void* {
    void* p = ws + off;
    off += (bytes + 255) & ~(size_t)255;
    return p;
  };
  const long BS  = (long)B_BATCH * S_LEN;         // 4096
  const long ZSD = (long)S_LEN * D_DIM;           // 524288
  const long ZSS = (long)S_LEN * S_LEN;           // 1048576
  const long SD  = BS * D_DIM;                    // 2097152 (one 4096x512 tensor)

  // --- workspace plan (207 MB of 256 MiB), with explicit aliasing ---
  bf16* WQT  = (bf16*)alloc(SD * 2);              // adjacent WQT,WKT (z-stride SD)
  bf16* WKT  = (bf16*)alloc(SD * 2);
  bf16* WVT  = (bf16*)alloc(SD * 2);
  bf16* WPQT = (bf16*)alloc((long)D_DIM * D_DIM * 2);  // adjacent WPQT,WPKT
  bf16* WPKT = (bf16*)alloc((long)D_DIM * D_DIM * 2);
  bf16* WPVT = (bf16*)alloc((long)D_DIM * D_DIM * 2);
  bf16* WOT3 = (bf16*)alloc((long)D_DIM * 3 * D_DIM * 2);
  bf16* XQ16 = (bf16*)alloc(SD * 2);              // adjacent XQ,XK (z-stride SD)
  bf16* XK16 = (bf16*)alloc(SD * 2);
  bf16* XV16 = (bf16*)alloc(SD * 2);
  bf16* MIX  = XQ16;                              // alias: dead after projections
  bf16* Q16  = (bf16*)alloc((long)H_HEADS * SD * 2);   // adjacent Q16,K16
  bf16* K16  = (bf16*)alloc((long)H_HEADS * SD * 2);
  float* X   = (float*)Q16;                       // alias: dead after scores
  bf16* VT16 = (bf16*)alloc((long)H_HEADS * SD * 2);
  bf16* QP16 = (bf16*)alloc(SD * 2);              // adjacent QP,KP
  bf16* KP16 = (bf16*)alloc(SD * 2);
  float* XP  = (float*)QP16;                      // alias: dead after scores_p
  bf16* VPT16= (bf16*)alloc(SD * 2);
  bf16* SC   = (bf16*)alloc((long)B_BATCH * H_HEADS * ZSS * 2);
  bf16* SCP  = (bf16*)alloc((long)B_BATCH * ZSS * 2);
  (void)in_sizes; (void)n_in; (void)out_size; (void)SCP;

  if (off > ws_size) return;  // clean diagnostic failure, never OOB

  const dim3 blk(256);
  const dim3 blk512(512);
  const float scale = 0.044194173824159216f;  // 1/sqrt(512)

  // 1. inputs -> bf16
  cvt3_kernel<<<dim3(1024, 1, 3), blk, 0, stream>>>(query, key, value, XQ16, XK16, XV16);
  // 2. weights -> transposed bf16
  transpose_cvt3<0><<<dim3(128, 16, 3), blk, 0, stream>>>(Wq, Wk, Wv, WQT, WKT, WVT, 512, 4096);
  transpose_cvt3<0><<<dim3(16, 16, 3), blk, 0, stream>>>(Wpq, Wpk, Wpv, WPQT, WPKT, WPVT, 512, 512);
  transpose_cvt3<1><<<dim3(16, 16, 1), blk, 0, stream>>>(Wo, Wo, Wo, WOT3, WOT3, WOT3, 512, 512);

  // 3. projections (M=4096) — big shapes on the 256^2 pipelined kernel
  gemm256_bt<1><<<dim3(16, 16, 2), blk512, 0, stream>>>(XQ16, WQT, Q16, bq, bk, nullptr,
      4096, 512, SD, SD, (long)H_HEADS * SD, 1.f, H_HEADS);
  gemm256_bt<2><<<dim3(16, 16, 1), blk512, 0, stream>>>(XV16, WVT, VT16, bv, nullptr, nullptr,
      4096, 512, 0, 0, 0, 1.f, H_HEADS);
  //    p-branch (small N) on the 128^2 kernel
  gemm_bt<0><<<dim3(32, 4, 2), blk, 0, stream>>>(XQ16, WPQT, QP16, bpq, bpk, nullptr,
      512, 512, SD, (long)D_DIM * D_DIM, SD, 1.f, 1);
  gemm_bt<2><<<dim3(32, 4, 1), blk, 0, stream>>>(XV16, WPVT, VPT16, bpv, nullptr, nullptr,
      512, 512, 0, 0, 0, 1.f, 1);

  // 4. scores = QK^T * scale, masked (z = b*H+h for main, b for p)
  gemm256_bt<4><<<dim3(4, 4, 32), blk512, 0, stream>>>(Q16, K16, SC, nullptr, nullptr, mask,
      1024, 512, ZSD, ZSD, ZSS, scale, H_HEADS);
  gemm_bt<4><<<dim3(8, 8, 4), blk, 0, stream>>>(QP16, KP16, SCP, nullptr, nullptr, mask_p,
      1024, 512, ZSD, ZSD, ZSS, scale, 1);

  // 5. softmax over SC and SCP together (adjacent rows)
  softmax_rows<<<dim3(32768 + 4096), blk, 0, stream>>>(SC);

  // 6. x = P @ V  (fp32 out; X aliases Q16/K16 — dead after step 4)
  gemm256_bt<3><<<dim3(4, 2, 32), blk512, 0, stream>>>(SC, VT16, X, nullptr, nullptr, nullptr,
      512, 1024, ZSS, ZSD, ZSD, 1.f, 1);
  gemm_bt<3><<<dim3(8, 4, 4), blk, 0, stream>>>(SCP, VPT16, XP, nullptr, nullptr, nullptr,
      512, 1024, ZSS, ZSD, ZSD, 1.f, 1);

  // 7. dis / head softmax / mix -> [hi|lo|hi] rows (MIX aliases XQ/XK/XV)
  combine_kernel<<<dim3(4096), blk, 0, stream>>>(X, XP, MIX);

  // 8. out = [m_hi|m_lo|m_hi] @ [Wo_hi|Wo_hi|Wo_lo]^T + bo  (fp32 out)
  gemm_bt<3><<<dim3(32, 4, 1), blk, 0, stream>>>(MIX, WOT3, d_out, bo, nullptr, nullptr,
      512, 1536, 0, 0, 0, 1.f, 1);
}